// Round 1
// baseline (3575.134 us; speedup 1.0000x reference)
//
#include <hip/hip_runtime.h>
#include <math.h>

// ---------------- types ----------------
typedef _Float16 f16;
typedef _Float16 f16x8 __attribute__((ext_vector_type(8)));
typedef float f32x4 __attribute__((ext_vector_type(4)));

#define DEV static __device__ __forceinline__

DEV float sigm(float x)  { return 1.0f / (1.0f + __expf(-x)); }
DEV float tanhfast(float x) { return 2.0f / (1.0f + __expf(-2.0f * x)) - 1.0f; }

// ---------------- problem constants ----------------
// B=256 V=50 N=32 D=128 H=384 L=12 CS=10 ND=4096 G=1560 OUT=128
#define GP 1664   // padded G for XK gemm (mult of 128)
#define GN 1600   // padded G for recurrence (25 tiles of 16 per wave)
#define RK 416    // padded rec K (385 -> 416, mult of 32)
#define KH 3840   // H*CS (conv gemm K)
#define KO 19200  // V*H  (out gemm K)

// ---------------- workspace layout (bytes) ----------------
// region sizes
//  x_f16   : 12800*4096*2 = 104857600   (reused later by lh_f16: 12800*3840*2 = 98304000)
//  Wk_f16  : 1664*4096*2  = 13631488
//  XK_f32  : 12800*1664*4 = 85196800    (reused later by mlh/s1/theme/conv)
//  RW_f16  : 1600*416*2   = 1331200
//  biasc   : 8192, kwlast : 8192
//  h_all   : 50*256*384*4 = 19660800
//  ld      : 12800*10*4   = 512000
//  Wc2_f16 : 384*3840*2   = 2949120
//  rnn_f16 : 256*19200*2  = 9830400
//  outw_f16: 128*19200*2  = 4915200
static constexpr size_t OFF_X     = 0;
static constexpr size_t OFF_LH    = 0;                       // aliases x (x dead after XK gemm)
static constexpr size_t OFF_WK    = 104857600;
static constexpr size_t OFF_XK    = OFF_WK + 13631488;       // 118489088
static constexpr size_t OFF_MLH   = OFF_XK;                  // aliases XK (dead after recurrence)
static constexpr size_t OFF_S1    = OFF_XK + 19660800;
static constexpr size_t OFF_TH    = OFF_S1 + 3276800;
static constexpr size_t OFF_CV    = OFF_TH + 19660800;       // ends < OFF_XK + 85196800
static constexpr size_t OFF_RW    = OFF_XK + 85196800;       // 203685888
static constexpr size_t OFF_BIASC = OFF_RW + 1331200;
static constexpr size_t OFF_KWL   = OFF_BIASC + 8192;
static constexpr size_t OFF_HALL  = OFF_KWL + 8192;
static constexpr size_t OFF_LD    = OFF_HALL + 19660800;
static constexpr size_t OFF_WC2   = OFF_LD + 512000;
static constexpr size_t OFF_RNN   = OFF_WC2 + 2949120;
static constexpr size_t OFF_OUTW  = OFF_RNN + 9830400;

// ---------------- kernels ----------------

// embedding gather -> x_f16 (12800 x 4096), 8 halfs / thread
__global__ __launch_bounds__(256) void k_gather(const int* __restrict__ ids,
                                                const float* __restrict__ embed,
                                                f16* __restrict__ xf) {
  int i = blockIdx.x * 256 + threadIdx.x;     // 12800*512 total
  int row = i >> 9;
  int c8  = i & 511;
  int n = c8 >> 4;
  int d = (c8 & 15) << 3;
  int id = ids[row * 32 + n];
  const float* e = embed + (long)id * 128 + d;
  float4 a = *(const float4*)e;
  float4 b = *(const float4*)(e + 4);
  f16x8 o;
  o[0]=(f16)a.x; o[1]=(f16)a.y; o[2]=(f16)a.z; o[3]=(f16)a.w;
  o[4]=(f16)b.x; o[5]=(f16)b.y; o[6]=(f16)b.z; o[7]=(f16)b.w;
  *(f16x8*)(xf + ((long)row << 12) + (c8 << 3)) = o;
}

// kernel_w (1560 x 4097) -> Wk_f16 (1664 x 4096, zero-padded rows), biasc = kb+rb, kwlast = col 4096
__global__ __launch_bounds__(256) void k_prep_wk(const float* __restrict__ kw,
                                                 const float* __restrict__ kb,
                                                 const float* __restrict__ rb,
                                                 f16* __restrict__ Wk,
                                                 float* __restrict__ biasc,
                                                 float* __restrict__ kwlast) {
  long i = (long)blockIdx.x * 256 + threadIdx.x;
  if (i < 1664L * 4096) {
    int nn = (int)(i >> 12);
    int k  = (int)(i & 4095);
    float v = (nn < 1560) ? kw[(long)nn * 4097 + k] : 0.0f;
    Wk[i] = (f16)v;
  }
  if (i < 1560) {
    biasc[i]  = kb[i] + rb[i];
    kwlast[i] = kw[(long)i * 4097 + 4096];
  }
}

// rec_w (1560 x 385) -> RW_f16 (1600 x 416, zero-padded)
__global__ __launch_bounds__(256) void k_prep_rw(const float* __restrict__ rw,
                                                 f16* __restrict__ RW) {
  long i = (long)blockIdx.x * 256 + threadIdx.x;
  if (i >= 1600L * 416) return;
  int nn = (int)(i / 416);
  int k  = (int)(i - (long)nn * 416);
  float v = 0.0f;
  if (nn < 1560 && k < 385) v = rw[(long)nn * 385 + k];
  RW[i] = (f16)v;
}

// conv_w (384,384,10) -> Wc2_f16[o][j*384+h]
__global__ __launch_bounds__(256) void k_prep_wc(const float* __restrict__ cw,
                                                 f16* __restrict__ Wc2) {
  int i = blockIdx.x * 256 + threadIdx.x;     // 384*3840
  if (i >= 384 * 3840) return;
  int o = i / 3840;
  int c = i - o * 3840;
  int j = c / 384;
  int h = c - j * 384;
  Wc2[i] = (f16)cw[((long)o * 384 + h) * 10 + j];
}

// generic fp32 -> f16 convert
__global__ __launch_bounds__(256) void k_cvt(const float* __restrict__ src,
                                             f16* __restrict__ dst, long n) {
  long i = (long)blockIdx.x * 256 + threadIdx.x;
  if (i < n) dst[i] = (f16)src[i];
}

// C(M x N) = A(M x K) * W(N x K)^T (+bias[col]); M,N mult of 128, K mult of 32.
// 256 threads = 4 waves in 2x2; wave computes 64x64 via 4x4 MFMA 16x16x32 f16 tiles.
__global__ __launch_bounds__(256) void k_gemm_bt(const f16* __restrict__ A,
                                                 const f16* __restrict__ W,
                                                 float* __restrict__ C,
                                                 const float* __restrict__ bias,
                                                 int N, int K) {
  __shared__ f16 As[128 * 40];   // LDS stride 40 halfs: 2-way-only bank aliasing (free)
  __shared__ f16 Bs[128 * 40];
  const int tid = threadIdx.x;
  const long rowA0 = (long)blockIdx.x * 128;
  const long rowB0 = (long)blockIdx.y * 128;
  const int w = tid >> 6, lane = tid & 63;
  const int q = lane >> 4, r16 = lane & 15;
  const int wr = w >> 1, wc = w & 1;
  f32x4 acc[4][4] = {};
  const int srow = tid >> 2;
  const int skc  = (tid & 3) * 8;
  const long aoff = (rowA0 + srow) * (long)K + skc;
  const long boff = (rowB0 + srow) * (long)K + skc;
  for (int k0 = 0; k0 < K; k0 += 32) {
    __syncthreads();
    *(f16x8*)&As[srow * 40 + skc]        = *(const f16x8*)(A + aoff + k0);
    *(f16x8*)&As[(srow + 64) * 40 + skc] = *(const f16x8*)(A + aoff + 64L * K + k0);
    *(f16x8*)&Bs[srow * 40 + skc]        = *(const f16x8*)(W + boff + k0);
    *(f16x8*)&Bs[(srow + 64) * 40 + skc] = *(const f16x8*)(W + boff + 64L * K + k0);
    __syncthreads();
    f16x8 af[4], bfr[4];
#pragma unroll
    for (int i = 0; i < 4; i++) {
      af[i]  = *(const f16x8*)&As[(wr * 64 + i * 16 + r16) * 40 + q * 8];
      bfr[i] = *(const f16x8*)&Bs[(wc * 64 + i * 16 + r16) * 40 + q * 8];
    }
#pragma unroll
    for (int i = 0; i < 4; i++)
#pragma unroll
      for (int j = 0; j < 4; j++)
        acc[i][j] = __builtin_amdgcn_mfma_f32_16x16x32_f16(af[i], bfr[j], acc[i][j], 0, 0, 0);
  }
  // epilogue: C[row=q*4+r][col=lane&15] per 16x16 tile (m89-verified layout)
#pragma unroll
  for (int i = 0; i < 4; i++)
#pragma unroll
    for (int j = 0; j < 4; j++) {
      long row = rowA0 + wr * 64 + i * 16 + q * 4;
      long col = rowB0 + wc * 64 + j * 16 + r16;
      float bv = bias ? bias[col] : 0.0f;
#pragma unroll
      for (int r = 0; r < 4; r++)
        C[(row + r) * (long)N + col] = acc[i][j][r] + bv;
    }
}

// the sequential scan: 32 blocks x 8 batch rows, 50 steps, no grid sync needed
// (recurrent state is independent per batch row).
__global__ __launch_bounds__(256) void k_recur(const float* __restrict__ XK,   // (12800, 1664)
                                               const f16* __restrict__ RW,    // (1600, 416)
                                               const float* __restrict__ biasc,
                                               const float* __restrict__ kwlast,
                                               const float* __restrict__ timep, // (256,50)
                                               float* __restrict__ h_all,       // (50,256,384)
                                               float* __restrict__ dists) {     // (50,256)
  __shared__ float xo[8 * GN];       // 51200 B
  __shared__ f16 hext[16 * 424];     // 13568 B  (rows 8..15 stay zero)
  const int tid = threadIdx.x;
  const int b0 = blockIdx.x * 8;
  for (int i = tid; i < 16 * 424; i += 256) hext[i] = (f16)0.0f;
  __syncthreads();
  if (tid < 8) hext[tid * 424 + 384] = (f16)timep[(b0 + tid) * 50];  // iv for t=0
  const int lane = tid & 63, w = tid >> 6;
  const int q = lane >> 4, r16 = lane & 15;
  const int m = tid >> 5, ch = tid & 31;    // gate-phase mapping: 8 groups x 32 lanes
  float creg[12];
#pragma unroll
  for (int l = 0; l < 12; l++) creg[l] = 0.0f;

  for (int t = 0; t < 50; t++) {
    __syncthreads();   // hext ready
    // ---- rec GEMM: xo[0:8][0:1600] = hext(16x416) @ RW^T  (rows 8..15 discarded)
    f16x8 af[13];
    const f16* hrow = hext + r16 * 424 + q * 8;
#pragma unroll
    for (int kt = 0; kt < 13; kt++) af[kt] = *(const f16x8*)(hrow + kt * 32);
    for (int nt = 0; nt < 25; nt++) {
      int n0 = w * 400 + nt * 16;
      const f16* wrow = RW + (long)(n0 + r16) * RK + q * 8;
      f32x4 a0 = {}, a1 = {};
#pragma unroll
      for (int kt = 0; kt < 12; kt += 2) {
        f16x8 bu = *(const f16x8*)(wrow + kt * 32);
        f16x8 bv = *(const f16x8*)(wrow + (kt + 1) * 32);
        a0 = __builtin_amdgcn_mfma_f32_16x16x32_f16(af[kt],     bu, a0, 0, 0, 0);
        a1 = __builtin_amdgcn_mfma_f32_16x16x32_f16(af[kt + 1], bv, a1, 0, 0, 0);
      }
      {
        f16x8 bu = *(const f16x8*)(wrow + 12 * 32);
        a0 = __builtin_amdgcn_mfma_f32_16x16x32_f16(af[12], bu, a0, 0, 0, 0);
      }
#pragma unroll
      for (int r = 0; r < 4; r++) {
        int rr = q * 4 + r;
        if (rr < 8) xo[rr * GN + n0 + r16] = a0[r] + a1[r];
      }
    }
    __syncthreads();
    // ---- fuse: xo += XK + (kernel_b+rec_b) + time*kw_last
    for (int idx = tid; idx < 8 * 1560; idx += 256) {
      int mm = idx / 1560, n = idx - mm * 1560;
      int b = b0 + mm;
      float tv = timep[b * 50 + t];
      xo[mm * GN + n] += XK[((long)b * 50 + t) * GP + n] + biasc[n] + tv * kwlast[n];
    }
    __syncthreads();
    // ---- gates (thread = (batch m, channel ch)); fm/im computed redundantly per lane
    {
      const float* xom = xo + m * GN;
      int b = b0 + m;
      float e1[12], e2[12], fm[12], im[12];
      float mx1 = -1e30f, mx2 = -1e30f;
#pragma unroll
      for (int l = 0; l < 12; l++) {
        mx1 = fmaxf(mx1, xom[l]);
        mx2 = fmaxf(mx2, xom[12 + l]);
      }
      float ss1 = 0.0f, ss2 = 0.0f;
#pragma unroll
      for (int l = 0; l < 12; l++) {
        e1[l] = __expf(xom[l] - mx1);      ss1 += e1[l];
        e2[l] = __expf(xom[12 + l] - mx2); ss2 += e2[l];
      }
      float i1 = 1.0f / ss1, i2 = 1.0f / ss2;
      float cum = 0.0f;
#pragma unroll
      for (int l = 0; l < 12; l++) { cum += e1[l]; fm[l] = cum * i1; }
      float cum2 = 0.0f;
#pragma unroll
      for (int l = 11; l >= 0; l--) { cum2 += e2[l]; im[l] = cum2 * i2; }
      float dsum = 0.0f;
#pragma unroll
      for (int l = 0; l < 12; l++) dsum += fm[l];
      float dist = 1.0f - dsum * (1.0f / 12.0f);

      float* hdst = h_all + ((long)t * 256 + b) * 384 + ch;
#pragma unroll
      for (int l = 0; l < 12; l++) {
        float fv  = sigm(xom[24 + l * 32 + ch]);
        float iv  = sigm(xom[24 + (12 + l) * 32 + ch]);
        float og  = sigm(xom[24 + (24 + l) * 32 + ch]);
        float ci  = tanhfast(xom[24 + (36 + l) * 32 + ch]);
        float fmv = fm[l], imv = im[l], ovl = fmv * imv;
        float cl = creg[l];
        float cn = ovl * (fv * cl + iv * ci) + (fmv - ovl) * cl + (imv - ovl) * ci;
        creg[l] = cn;
        float hv = og * tanhfast(cn);
        hdst[l * 32] = hv;
        hext[m * 424 + l * 32 + ch] = (f16)hv;
      }
      if (ch == 0) dists[t * 256 + b] = dist;
      if (ch == 1 && t < 49) hext[m * 424 + 384] = (f16)timep[b * 50 + t + 1];
    }
  }
}

// ld[b,t,:] = softmax_j(cumsum_j dist[t-9+j])
__global__ __launch_bounds__(256) void k_ld(const float* __restrict__ dists,
                                            float* __restrict__ ld) {
  int i = blockIdx.x * 256 + threadIdx.x;
  if (i >= 12800) return;
  int b = i / 50, t = i - b * 50;
  float v[10];
  float cum = 0.0f, mx = -1e30f;
#pragma unroll
  for (int j = 0; j < 10; j++) {
    int s = t - 9 + j;
    float d = (s >= 0) ? dists[s * 256 + b] : 0.0f;
    cum += d; v[j] = cum; mx = fmaxf(mx, cum);
  }
  float sum = 0.0f;
#pragma unroll
  for (int j = 0; j < 10; j++) { v[j] = __expf(v[j] - mx); sum += v[j]; }
  float inv = 1.0f / sum;
#pragma unroll
  for (int j = 0; j < 10; j++) ld[i * 10 + j] = v[j] * inv;
}

// lh_f16[(b,t)][j*384+h] = ld[b,t,j] * h_{t-9+j}[b,h]
__global__ __launch_bounds__(256) void k_lh(const float* __restrict__ ld,
                                            const float* __restrict__ h_all,
                                            f16* __restrict__ lh) {
  int i = blockIdx.x * 256 + threadIdx.x;   // 12800*480
  int row = i / 480;
  int c = i - row * 480;
  int j = c / 48;
  int h0 = (c - j * 48) * 8;
  int b = row / 50, t = row - b * 50;
  int s = t - 9 + j;
  f16x8 o;
  if (s >= 0) {
    float wv = ld[row * 10 + j];
    const float* hp = h_all + ((long)s * 256 + b) * 384 + h0;
#pragma unroll
    for (int k = 0; k < 8; k++) o[k] = (f16)(wv * hp[k]);
  } else {
#pragma unroll
    for (int k = 0; k < 8; k++) o[k] = (f16)0.0f;
  }
  *(f16x8*)(lh + (long)row * KH + j * 384 + h0) = o;
}

// mlh[(b,t)][h] = mean_j lh
__global__ __launch_bounds__(256) void k_mlh(const float* __restrict__ ld,
                                             const float* __restrict__ h_all,
                                             float* __restrict__ mlh) {
  int i = blockIdx.x * 256 + threadIdx.x;   // 12800*384
  int row = i / 384, h = i - row * 384;
  int b = row / 50, t = row - b * 50;
  float acc = 0.0f;
#pragma unroll
  for (int j = 0; j < 10; j++) {
    int s = t - 9 + j;
    if (s >= 0) acc += ld[row * 10 + j] * h_all[((long)s * 256 + b) * 384 + h];
  }
  mlh[i] = acc * 0.1f;
}

// s1 = relu(mlh @ scale_w^T + scale_b), (12800 x 64)
__global__ __launch_bounds__(256) void k_scale1(const float* __restrict__ mlh,
                                                const float* __restrict__ sw,
                                                const float* __restrict__ sb,
                                                float* __restrict__ s1) {
  int i = blockIdx.x * 256 + threadIdx.x;   // 12800*64
  int row = i >> 6, o = i & 63;
  const float* a = mlh + (long)row * 384;
  const float* wv = sw + o * 384;
  float acc = 0.0f;
  for (int k = 0; k < 384; k += 4)
    acc += a[k] * wv[k] + a[k + 1] * wv[k + 1] + a[k + 2] * wv[k + 2] + a[k + 3] * wv[k + 3];
  s1[i] = fmaxf(acc + sb[o], 0.0f);
}

// theme = sigmoid(s1 @ rescale_w^T + rescale_b), (12800 x 384)
__global__ __launch_bounds__(256) void k_scale2(const float* __restrict__ s1,
                                                const float* __restrict__ rw,
                                                const float* __restrict__ rb,
                                                float* __restrict__ theme) {
  int i = blockIdx.x * 256 + threadIdx.x;   // 12800*384
  int row = i / 384, o = i - row * 384;
  const float* a = s1 + (long)row * 64;
  const float* wv = rw + o * 64;
  float acc = 0.0f;
  for (int k = 0; k < 64; k += 4)
    acc += a[k] * wv[k] + a[k + 1] * wv[k + 1] + a[k + 2] * wv[k + 2] + a[k + 3] * wv[k + 3];
  theme[i] = sigm(acc + rb[o]);
}

// rnn_f16[b][t*384+h] = theme*conv + h
__global__ __launch_bounds__(256) void k_rnn(const float* __restrict__ theme,
                                             const float* __restrict__ conv,
                                             const float* __restrict__ h_all,
                                             f16* __restrict__ rnn) {
  int i = blockIdx.x * 256 + threadIdx.x;   // 12800*384, ordered (b,t,h)
  int row = i / 384, h = i - row * 384;
  int b = row / 50, t = row - b * 50;
  float local = theme[i] * conv[i];
  float hv = h_all[((long)t * 256 + b) * 384 + h];
  rnn[i] = (f16)(local + hv);               // (b*50+t)*384+h == b*19200 + t*384 + h
}

// ---------------- launch ----------------
extern "C" void kernel_launch(void* const* d_in, const int* in_sizes, int n_in,
                              void* d_out, int out_size, void* d_ws, size_t ws_size,
                              hipStream_t stream) {
  (void)in_sizes; (void)n_in; (void)out_size; (void)ws_size;
  const int*   node_ids  = (const int*)  d_in[0];
  const float* timep     = (const float*)d_in[3];
  const float* embed     = (const float*)d_in[6];
  const float* kernel_w  = (const float*)d_in[7];
  const float* kernel_b  = (const float*)d_in[8];
  const float* rec_w     = (const float*)d_in[9];
  const float* rec_b     = (const float*)d_in[10];
  const float* scale_w   = (const float*)d_in[11];
  const float* scale_b   = (const float*)d_in[12];
  const float* rescale_w = (const float*)d_in[13];
  const float* rescale_b = (const float*)d_in[14];
  const float* conv_w    = (const float*)d_in[15];
  const float* conv_b    = (const float*)d_in[16];
  const float* out_w     = (const float*)d_in[17];
  const float* out_b     = (const float*)d_in[18];

  char* ws = (char*)d_ws;
  f16*   xf      = (f16*)  (ws + OFF_X);
  f16*   lh      = (f16*)  (ws + OFF_LH);
  f16*   Wk      = (f16*)  (ws + OFF_WK);
  float* XK      = (float*)(ws + OFF_XK);
  float* mlh     = (float*)(ws + OFF_MLH);
  float* s1      = (float*)(ws + OFF_S1);
  float* theme   = (float*)(ws + OFF_TH);
  float* convbuf = (float*)(ws + OFF_CV);
  f16*   RW      = (f16*)  (ws + OFF_RW);
  float* biasc   = (float*)(ws + OFF_BIASC);
  float* kwlast  = (float*)(ws + OFF_KWL);
  float* h_all   = (float*)(ws + OFF_HALL);
  float* ldbuf   = (float*)(ws + OFF_LD);
  f16*   Wc2     = (f16*)  (ws + OFF_WC2);
  f16*   rnn     = (f16*)  (ws + OFF_RNN);
  f16*   outw    = (f16*)  (ws + OFF_OUTW);

  float* outp  = (float*)d_out;          // (256,128)
  float* dists = outp + 256 * 128;       // (50,256)

  // phase 0: prep
  k_gather <<<25600, 256, 0, stream>>>(node_ids, embed, xf);
  k_prep_wk<<<26624, 256, 0, stream>>>(kernel_w, kernel_b, rec_b, Wk, biasc, kwlast);
  k_prep_rw<<<2600,  256, 0, stream>>>(rec_w, RW);
  // phase 1: XK = x @ kernel_w^T  (hoisted out of the scan)
  k_gemm_bt<<<dim3(100, 13), 256, 0, stream>>>(xf, Wk, XK, nullptr, GP, 4096);
  // phase 2: sequential recurrence (per-batch independent)
  k_recur<<<32, 256, 0, stream>>>(XK, RW, biasc, kwlast, timep, h_all, dists);
  // phase 3: deferred outputs (fully parallel)
  k_ld  <<<50,    256, 0, stream>>>(dists, ldbuf);
  k_lh  <<<24000, 256, 0, stream>>>(ldbuf, h_all, lh);
  k_mlh <<<19200, 256, 0, stream>>>(ldbuf, h_all, mlh);
  k_scale1<<<3200,  256, 0, stream>>>(mlh, scale_w, scale_b, s1);
  k_scale2<<<19200, 256, 0, stream>>>(s1, rescale_w, rescale_b, theme);
  k_prep_wc<<<5760, 256, 0, stream>>>(conv_w, Wc2);
  k_gemm_bt<<<dim3(100, 3), 256, 0, stream>>>(lh, Wc2, convbuf, conv_b, 384, KH);
  k_rnn <<<19200, 256, 0, stream>>>(theme, convbuf, h_all, rnn);
  k_cvt <<<9600,  256, 0, stream>>>(out_w, outw, 128L * KO);
  // phase 4: out = rnn @ out_w^T + out_b
  k_gemm_bt<<<dim3(2, 1), 256, 0, stream>>>(rnn, outw, outp, out_b, 128, KO);
}